// Round 9
// baseline (1347.540 us; speedup 1.0000x reference)
//
#include <hip/hip_runtime.h>
#include <hip/hip_bf16.h>

#define D_  512
#define H_  8
#define DH_ 64
#define L_  6
#define FF_ 2048
#define V_  4096
#define B_  2
#define S_  4096
#define SB_ (S_*B_)   // 8192 tokens
#define DD_ ((size_t)D_*D_)
#define FD_ ((size_t)FF_*D_)
#define NTOT_ (4*DD_ + 2*FD_)   // per-layer converted weight elems (3,145,728)
#define CVT_BLKS_ 20480         // blocks doing weight conversion in prep_all

typedef unsigned short u16;
typedef unsigned int   u32;
typedef _Float16 f16;
typedef f16   f16x8 __attribute__((ext_vector_type(8)));
typedef float f32x4 __attribute__((ext_vector_type(4)));

__device__ __forceinline__ float us2f(u16 u){          // bf16 bits -> float
  union { u32 i; float f; } c; c.i = ((u32)u) << 16; return c.f;
}
__device__ __forceinline__ u16 f2b(float f){           // float -> bf16 bits (RNE)
  union { float f; u32 i; } c; c.f = f;
  u32 x = c.i;
  x += 0x7FFF + ((x >> 16) & 1);
  return (u16)(x >> 16);
}
__device__ __forceinline__ float h2f(u16 u){           // fp16 bits -> float
  union { u16 s; f16 h; } c; c.s = u; return (float)c.h;
}
__device__ __forceinline__ u16 f2h(float f){           // float -> fp16 bits (RNE)
  union { f16 h; u16 s; } c; c.h = (f16)f; return c.s;
}
// load element i of external tensor p: bf16 if isbf else fp32
__device__ __forceinline__ float ldf(const void* p, size_t i, int isbf){
  return isbf ? us2f(((const u16*)p)[i]) : ((const float*)p)[i];
}

typedef const __attribute__((address_space(1))) u32* gas_u32p;
typedef       __attribute__((address_space(3))) u32* las_u32p;
// async 16B/lane global->LDS; LDS dest = wave-uniform base + lane*16
__device__ __forceinline__ void async16(const u16* g, u16* l){
  __builtin_amdgcn_global_load_lds((gas_u32p)(const void*)g, (las_u32p)(void*)l, 16, 0, 0);
}

// ---------------------------------------------------------------------------
// dtype sniffer (empirically: inputs are fp32 -> flag 0; kept for robustness)
// ---------------------------------------------------------------------------
__global__ __launch_bounds__(64) void detect_dtype(const void* emb, int* flag)
{
  const int t = threadIdx.x;
  u16 hw = ((const u16*)emb)[t];
  int e = (hw >> 7) & 0xFF;
  int ok = ((e > 96) && (e < 160)) || ((hw & 0x7FFF) == 0);
  unsigned long long m = __ballot(ok);
  if (t == 0) *flag = (__popcll(m) >= 56) ? 1 : 0;
}

// ---------------------------------------------------------------------------
// prep_all: ONE launch doing both independent prep steps (range-split):
//  blocks [0, CVT_BLKS_):       convert all weights (6 layers + Wfc) to fp16
//  blocks [CVT_BLKS_, +SB_):    embed  h/hb[(s*B+b)*D+d] = emb[tok*D+d]
// ---------------------------------------------------------------------------
__global__ __launch_bounds__(256) void prep_all(
    const void* Wq, const void* Wk, const void* Wv, const void* Wo,
    const void* W1, const void* W2, const void* Wfc,
    u16* __restrict__ dstAll, u16* __restrict__ dstFC,
    const int* __restrict__ inp, const void* emb,
    float* __restrict__ h, u16* __restrict__ hb, const int* flagp)
{
  const int isbf = *flagp;
  if (blockIdx.x >= CVT_BLKS_) {
    const int m = blockIdx.x - CVT_BLKS_;        // token index s*B + b
    const int t = threadIdx.x;
    const int s = m >> 1, b = m & 1;
    const int tok = inp[b * S_ + s];
    #pragma unroll
    for (int hh = 0; hh < 2; hh++) {
      const int d = t + hh * 256;
      const float v = ldf(emb, (size_t)tok * D_ + d, isbf);
      h[(size_t)m * D_ + d] = v;
      hb[(size_t)m * D_ + d] = f2h(v);
    }
    return;
  }
  const size_t total6 = 6 * NTOT_;
  const size_t i = ((size_t)blockIdx.x * 256 + threadIdx.x) * 4;
  const void* src; size_t off; u16* dst;
  if (i < total6) {
    const int l = (int)(i / NTOT_);
    const size_t r = i - (size_t)l * NTOT_;
    const size_t n4 = 4 * DD_, nW1 = n4 + FD_;
    if (r < n4) {
      const int wsel = (int)(r / DD_);
      src = (wsel == 0) ? Wq : (wsel == 1) ? Wk : (wsel == 2) ? Wv : Wo;
      off = (size_t)l * DD_ + (r - (size_t)wsel * DD_);
    } else if (r < nW1) { src = W1; off = (size_t)l * FD_ + (r - n4); }
    else                { src = W2; off = (size_t)l * FD_ + (r - nW1); }
    dst = dstAll + i;
  } else {
    const size_t j = i - total6;
    if (j >= (size_t)V_ * D_) return;
    src = Wfc; off = j; dst = dstFC + j;
  }
  ushort4 o;
  if (isbf) {
    ushort4 u = *(const ushort4*)((const u16*)src + off);
    o = make_ushort4(f2h(us2f(u.x)), f2h(us2f(u.y)), f2h(us2f(u.z)), f2h(us2f(u.w)));
  } else {
    float4 f = *(const float4*)((const float*)src + off);
    o = make_ushort4(f2h(f.x), f2h(f.y), f2h(f.z), f2h(f.w));
  }
  *(ushort4*)dst = o;
}

// ---------------------------------------------------------------------------
// PERSISTENT MFMA GEMM, BM=128 x BN=128, K=512 fixed (NT=16 k-steps/tile).
// Each block processes TPB output tiles with ONE continuous counted-vmcnt
// pipeline.  Tile order: v = blockIdx.x*TPB + g;
//   by = v >> LOG_TXZ (A-panel row tile; CONSTANT within a block),
//   bz = (v & (TXZ-1)) >> LOG_TX,  bx = v & (TX-1).
// Bias preloaded into registers BEFORE any staging.
//  OUTMODE 0: fp16 Cb[m*N+n], bias per-n (+relu if ACT)
//  OUTMODE 3: flag-dtype Cout[bz*M*N + m*N + n], bias per-m
// ---------------------------------------------------------------------------
template<int ACT, int OUTMODE, int PRE, int TPB, int LOG_TX, int LOG_TXZ>
__global__ __launch_bounds__(256) void gemm_pers(
    const u16* __restrict__ A, const u16* __restrict__ Bm,
    int bstride,
    const void* bias, size_t bias_off,
    u16* __restrict__ Cb, void* __restrict__ Cout,
    int M, int N, int K, const int* flagp)
{
  __shared__ u16 tile[(PRE + 1) * 8192];  // per buf: A [0,4096), B [4096,8192)
  const int t = threadIdx.x, lane = t & 63, w = t >> 6;
  const int wr = w >> 1, wc = w & 1;
  const int col = lane & 15, quad = lane >> 4;
  const int srow = w * 16 + (lane >> 2);
  const int skol = (((lane & 3) ^ ((lane >> 3) & 3)) << 3);
  const int rswz = ((col >> 1) & 3);
  const int isbf = *flagp;
  const int vbase = blockIdx.x * TPB;

  // ---- bias preload (before any staging: compiler wait is trivial here) ----
  float bpre3[(OUTMODE == 3) ? 16 : 1];
  float bpre0[(OUTMODE == 3) ? 1 : TPB][4];
  if (OUTMODE == 3) {
    const int by0 = vbase >> LOG_TXZ;            // same by for all TPB tiles
    #pragma unroll
    for (int i = 0; i < 4; i++)
      #pragma unroll
      for (int r = 0; r < 4; r++)
        bpre3[i * 4 + r] = ldf(bias, bias_off + (by0 << 7) + wr * 64 + i * 16 + quad * 4 + r, isbf);
  } else {
    #pragma unroll
    for (int g = 0; g < TPB; g++) {
      const int bxg = (vbase + g) & ((1 << LOG_TX) - 1);
      #pragma unroll
      for (int j = 0; j < 4; j++)
        bpre0[g][j] = ldf(bias, bias_off + (bxg << 7) + wc * 64 + j * 16 + col, isbf);
    }
  }

  // ---- stage-side tile pointers ----
  int st = -1;
  const u16 *ag0 = nullptr, *ag1 = nullptr, *bg0 = nullptr, *bg1 = nullptr;
  auto set_tile = [&](int tp) {
    const int v  = vbase + tp;
    const int by = v >> LOG_TXZ;
    const int rr = v & ((1 << LOG_TXZ) - 1);
    const int bz = rr >> LOG_TX;
    const int bx = rr & ((1 << LOG_TX) - 1);
    ag0 = A + (size_t)((by << 7) + srow) * K + skol;
    ag1 = ag0 + (size_t)64 * K;
    bg0 = Bm + ((size_t)((bx << 7) + srow) * bstride + bz) * K + skol;
    bg1 = bg0 + (size_t)64 * bstride * K;
  };
  auto stage = [&](int u) {
    const int tp = u >> 4;
    if (tp != st) { st = tp; set_tile(tp); }
    const int k0 = (u & 15) << 5;
    const int bo = (u % (PRE + 1)) * 8192;
    async16(ag0 + k0, &tile[bo +        w * 512]);
    async16(ag1 + k0, &tile[bo + 2048 + w * 512]);
    async16(bg0 + k0, &tile[bo + 4096 + w * 512]);
    async16(bg1 + k0, &tile[bo + 6144 + w * 512]);
  };

  const int U = TPB * 16;
  #pragma unroll
  for (int p = 0; p < PRE; ++p) stage(p);
  if (PRE >= 2) asm volatile("s_waitcnt vmcnt(4)" ::: "memory");
  else          asm volatile("s_waitcnt vmcnt(0)" ::: "memory");
  __builtin_amdgcn_s_barrier();
  asm volatile("" ::: "memory");

  f32x4 acc[4][4] = {};
  for (int u = 0; u < U; ++u) {
    if (u + PRE < U) stage(u + PRE);
    const int cur = (u % (PRE + 1)) * 8192;
    f16x8 af[4], bf[4];
    #pragma unroll
    for (int i = 0; i < 4; i++)
      af[i] = *(const f16x8*)&tile[cur + (wr * 64 + i * 16 + col) * 32 + ((quad ^ rswz) * 8)];
    #pragma unroll
    for (int j = 0; j < 4; j++)
      bf[j] = *(const f16x8*)&tile[cur + 4096 + (wc * 64 + j * 16 + col) * 32 + ((quad ^ rswz) * 8)];
    #pragma unroll
    for (int i = 0; i < 4; i++)
      #pragma unroll
      for (int j = 0; j < 4; j++)
        acc[i][j] = __builtin_amdgcn_mfma_f32_16x16x32_f16(af[i], bf[j], acc[i][j], 0, 0, 0);

    if ((u & 15) == 15) {
      // -------- epilogue for tile (u>>4); registers + stores only --------
      const int v  = vbase + (u >> 4);
      const int by = v >> LOG_TXZ;
      const int rr = v & ((1 << LOG_TXZ) - 1);
      const int bz = rr >> LOG_TX;
      const int bx = rr & ((1 << LOG_TX) - 1);
      const int bm = by << 7, bn = bx << 7;
      if (OUTMODE == 3) {
        const size_t obase = (size_t)bz * M * N;
        #pragma unroll
        for (int i = 0; i < 4; i++)
          #pragma unroll
          for (int r = 0; r < 4; r++) {
            const int m = bm + wr * 64 + i * 16 + quad * 4 + r;
            #pragma unroll
            for (int j = 0; j < 4; j++) {
              const int n = bn + wc * 64 + j * 16 + col;
              const float c = acc[i][j][r] + bpre3[i * 4 + r];
              const size_t oi = obase + (size_t)m * N + n;
              if (isbf) ((u16*)Cout)[oi] = f2b(c);
              else      ((float*)Cout)[oi] = c;
            }
          }
      } else {
        const int g = u >> 4;
        #pragma unroll
        for (int i = 0; i < 4; i++)
          #pragma unroll
          for (int r = 0; r < 4; r++) {
            const int m = bm + wr * 64 + i * 16 + quad * 4 + r;
            #pragma unroll
            for (int j = 0; j < 4; j++) {
              const int n = bn + wc * 64 + j * 16 + col;
              float c = acc[i][j][r] + bpre0[g][j];
              if (ACT == 1) c = fmaxf(c, 0.f);
              Cb[(size_t)m * N + n] = f2h(c);
            }
          }
      }
      const f32x4 z = {0.f, 0.f, 0.f, 0.f};
      #pragma unroll
      for (int i = 0; i < 4; i++)
        #pragma unroll
        for (int j = 0; j < 4; j++)
          acc[i][j] = z;
    }

    if (PRE >= 2 && u + 2 < U) asm volatile("s_waitcnt vmcnt(4)" ::: "memory");
    else                       asm volatile("s_waitcnt vmcnt(0)" ::: "memory");
    __builtin_amdgcn_s_barrier();
    asm volatile("" ::: "memory");
  }
}

// ---------------------------------------------------------------------------
// Fused QKV GEMM: N = 1536 (Wc holds q|k|v rows contiguous). grid (12, 64)
// -> 768 blocks = 3 blocks/CU. Epilogue per 64-col wave span (head-aligned):
//   cols 0-511 (Q): unit -> qb | 512-1023 (K): elu(unit) -> kb | 1024+ (V) -> vb
// PRE=2 counted-vmcnt pipeline.
// ---------------------------------------------------------------------------
__global__ __launch_bounds__(256) void gemm_qkv(
    const u16* __restrict__ A, const u16* __restrict__ Bm,
    const void* bq, const void* bk, const void* bv, size_t b_off,
    u16* __restrict__ qb, u16* __restrict__ kb, u16* __restrict__ vb,
    int K, const int* flagp)
{
  __shared__ u16 tile[3 * 8192];
  const int t = threadIdx.x, lane = t & 63, w = t >> 6;
  const int bm = blockIdx.y << 7, bn = blockIdx.x << 7;
  const int wr = w >> 1, wc = w & 1;
  const int col = lane & 15, quad = lane >> 4;

  const int srow = w * 16 + (lane >> 2);
  const int skol = (((lane & 3) ^ ((lane >> 3) & 3)) << 3);
  const u16* ag0 = A + (size_t)(bm + srow) * K + skol;
  const u16* ag1 = A + (size_t)(bm + 64 + srow) * K + skol;
  const u16* bg0 = Bm + (size_t)(bn + srow) * K + skol;
  const u16* bg1 = Bm + (size_t)(bn + 64 + srow) * K + skol;
  u16* la0 = &tile[       w * 512];
  u16* la1 = &tile[2048 + w * 512];
  u16* lb0 = &tile[4096 + w * 512];
  u16* lb1 = &tile[6144 + w * 512];

  const int nt = K >> 5;

  #pragma unroll
  for (int p = 0; p < 2; ++p) {
    const int k0 = p << 5, bo = p * 8192;
    async16(ag0 + k0, la0 + bo);
    async16(ag1 + k0, la1 + bo);
    async16(bg0 + k0, lb0 + bo);
    async16(bg1 + k0, lb1 + bo);
  }
  asm volatile("s_waitcnt vmcnt(4)" ::: "memory");
  __builtin_amdgcn_s_barrier();
  asm volatile("" ::: "memory");

  const int rswz = ((col >> 1) & 3);

  f32x4 acc[4][4] = {};
  for (int t2 = 0; t2 < nt; ++t2) {
    if (t2 + 2 < nt) {
      const int k0 = (t2 + 2) << 5;
      const int bo = ((t2 + 2) % 3) * 8192;
      async16(ag0 + k0, la0 + bo);
      async16(ag1 + k0, la1 + bo);
      async16(bg0 + k0, lb0 + bo);
      async16(bg1 + k0, lb1 + bo);
    }
    const int cur = (t2 % 3) * 8192;
    f16x8 af[4], bf[4];
    #pragma unroll
    for (int i = 0; i < 4; i++)
      af[i] = *(const f16x8*)&tile[cur + (wr * 64 + i * 16 + col) * 32 + ((quad ^ rswz) * 8)];
    #pragma unroll
    for (int j = 0; j < 4; j++)
      bf[j] = *(const f16x8*)&tile[cur + 4096 + (wc * 64 + j * 16 + col) * 32 + ((quad ^ rswz) * 8)];
    #pragma unroll
    for (int i = 0; i < 4; i++)
      #pragma unroll
      for (int j = 0; j < 4; j++)
        acc[i][j] = __builtin_amdgcn_mfma_f32_16x16x32_f16(af[i], bf[j], acc[i][j], 0, 0, 0);
    if (t2 + 2 < nt) asm volatile("s_waitcnt vmcnt(4)" ::: "memory");
    else             asm volatile("s_waitcnt vmcnt(0)" ::: "memory");
    __builtin_amdgcn_s_barrier();
    asm volatile("" ::: "memory");
  }

  const int isbf = *flagp;
  const int nbase = bn + wc * 64;       // 64-aligned -> head-aligned
  const int sel = nbase >> 9;           // 0=Q 1=K 2=V, wave-uniform
  const int nl0 = nbase & 511;          // local col base within the matrix
  u16* outp = (sel == 0) ? qb : (sel == 1) ? kb : vb;
  const void* bias = (sel == 0) ? bq : (sel == 1) ? bk : bv;

  if (sel < 2) {
    #pragma unroll
    for (int i = 0; i < 4; i++) {
      #pragma unroll
      for (int r = 0; r < 4; r++) {
        float v[4]; float ss = 0.f;
        #pragma unroll
        for (int j = 0; j < 4; j++) {
          const int nl = nl0 + j * 16 + col;
          v[j] = acc[i][j][r] + ldf(bias, b_off + nl, isbf);
          ss += v[j] * v[j];
        }
        ss += __shfl_xor(ss, 1); ss += __shfl_xor(ss, 2);
        ss += __shfl_xor(ss, 4); ss += __shfl_xor(ss, 8);
        const float inv = rsqrtf(fmaxf(ss, 1e-30f));
        const int m = bm + wr * 64 + i * 16 + quad * 4 + r;
        #pragma unroll
        for (int j = 0; j < 4; j++) {
          float u = v[j] * inv;
          if (sel == 1) u = (u > 0.f) ? u : expm1f(u);
          outp[(size_t)m * 512 + nl0 + j * 16 + col] = f2h(u);
        }
      }
    }
  } else {
    #pragma unroll
    for (int i = 0; i < 4; i++)
      #pragma unroll
      for (int r = 0; r < 4; r++) {
        const int m = bm + wr * 64 + i * 16 + quad * 4 + r;
        #pragma unroll
        for (int j = 0; j < 4; j++) {
          const int nl = nl0 + j * 16 + col;
          outp[(size_t)m * 512 + nl] = f2h(acc[i][j][r] + ldf(bias, b_off + nl, isbf));
        }
      }
  }
}

// ---------------------------------------------------------------------------
// MFMA GEMM, BM=64 x BN=128: thin-N (W2: N=512). 512 blocks = 2 blocks/CU.
// OUTMODE 2 = fp32 only (W2: fp16 hb write is dead, LN rewrites it).
// ---------------------------------------------------------------------------
template<int ACT, int OUTMODE, int PRE>
__global__ __launch_bounds__(256) void gemm_mfma64(
    const u16* __restrict__ A, const u16* __restrict__ Bm,
    const void* bias, size_t bias_off,
    const float* __restrict__ res,
    float* __restrict__ Cf, u16* __restrict__ Cb,
    int M, int N, int K, const int* flagp)
{
  __shared__ u16 tile[(PRE + 1) * 6144];  // per buf: A [0,2048), B [2048,6144)
  const int t = threadIdx.x, lane = t & 63, w = t >> 6;
  const int bm = blockIdx.y << 6, bn = blockIdx.x << 7;
  const int wr = w >> 1, wc = w & 1;
  const int col = lane & 15, quad = lane >> 4;

  const int srow = w * 16 + (lane >> 2);  // 0..63
  const int skol = (((lane & 3) ^ ((lane >> 3) & 3)) << 3);
  const u16* ag  = A + (size_t)(bm + srow) * K + skol;
  const u16* bg0 = Bm + (size_t)(bn + srow) * K + skol;
  const u16* bg1 = Bm + (size_t)(bn + 64 + srow) * K + skol;
  u16* la  = &tile[       w * 512];
  u16* lb0 = &tile[2048 + w * 512];
  u16* lb1 = &tile[4096 + w * 512];

  const int nt = K >> 5;

  #pragma unroll
  for (int p = 0; p < PRE; ++p) {
    const int k0 = p << 5, bo = p * 6144;
    async16(ag  + k0, la  + bo);
    async16(bg0 + k0, lb0 + bo);
    async16(bg1 + k0, lb1 + bo);
  }
  if      (PRE >= 3) asm volatile("s_waitcnt vmcnt(6)" ::: "memory");
  else if (PRE == 2) asm volatile("s_waitcnt vmcnt(3)" ::: "memory");
  else               asm volatile("s_waitcnt vmcnt(0)" ::: "memory");
  __builtin_amdgcn_s_barrier();
  asm volatile("" ::: "memory");

  const int rswz = ((col >> 1) & 3);

  f32x4 acc[2][4] = {};
  for (int t2 = 0; t2 < nt; ++t2) {
    if (t2 + PRE < nt) {
      const int k0 = (t2 + PRE) << 5;
      const int bo = ((t2 + PRE) % (PRE + 1)) * 6144;
      async16(ag  + k0, la  + bo);
      async16(bg0 + k0, lb0 + bo);
      async16(bg1 + k0, lb1 + bo);
    }
    const int cur = (t2 % (PRE + 1)) * 6144;
    f16x8 af[2], bf[4];
    #pragma unroll
    for (int i = 0; i < 2; i++)
      af[i] = *(const f16x8*)&tile[cur + (wr * 32 + i * 16 + col) * 32 + ((quad ^ rswz) * 8)];
    #pragma unroll
    for (int j = 0; j < 4; j++)
      bf[j] = *(const f16x8*)&tile[cur + 2048 + (wc * 64 + j * 16 + col) * 32 + ((quad ^ rswz) * 8)];
    #pragma unroll
    for (int i = 0; i < 2; i++)
      #pragma unroll
      for (int j = 0; j < 4; j++)
        acc[i][j] = __builtin_amdgcn_mfma_f32_16x16x32_f16(af[i], bf[j], acc[i][j], 0, 0, 0);
    if (PRE >= 3) {
      if      (t2 + 3 < nt) asm volatile("s_waitcnt vmcnt(6)" ::: "memory");
      else if (t2 + 2 < nt) asm volatile("s_waitcnt vmcnt(3)" ::: "memory");
      else                  asm volatile("s_waitcnt vmcnt(0)" ::: "memory");
    } else if (PRE == 2) {
      if (t2 + 2 < nt) asm volatile("s_waitcnt vmcnt(3)" ::: "memory");
      else             asm volatile("s_waitcnt vmcnt(0)" ::: "memory");
    } else {
      asm volatile("s_waitcnt vmcnt(0)" ::: "memory");
    }
    __builtin_amdgcn_s_barrier();
    asm volatile("" ::: "memory");
  }

  const int isbf = *flagp;
  #pragma unroll
  for (int i = 0; i < 2; i++) {
    #pragma unroll
    for (int r = 0; r < 4; r++) {
      const int m = bm + wr * 32 + i * 16 + quad * 4 + r;
      #pragma unroll
      for (int j = 0; j < 4; j++) {
        const int n = bn + wc * 64 + j * 16 + col;
        float c = acc[i][j][r] + ldf(bias, bias_off + n, isbf);
        if (res) c += res[(size_t)m * N + n];
        if (ACT == 1) c = fmaxf(c, 0.f);
        if (OUTMODE == 0) {
          Cb[(size_t)m * N + n] = f2h(c);
        } else if (OUTMODE == 1) {
          Cf[(size_t)m * N + n] = c;
          Cb[(size_t)m * N + n] = f2h(c);
        } else {   // OUTMODE 2: fp32 only
          Cf[(size_t)m * N + n] = c;
        }
      }
    }
  }
}

// ---------------------------------------------------------------------------
// gemm_wo: h[g] += q[g] @ W'[b]^T + bo   with g = (bm+m)*2 + bz (batch rows
// interleaved; bz = blockIdx.z = batch).  BM=64 x BN=128, K=512, PRE=3.
// Writes h fp32 + hb fp16.  Replaces attn_apply + Wo GEMM (W' = Wo folded
// with the attention matrix, computed by form_wp).
// ---------------------------------------------------------------------------
__global__ __launch_bounds__(256) void gemm_wo(
    const u16* __restrict__ A,       // qb: rows s*2+b, 512 cols
    const u16* __restrict__ Wp,      // wp: [b][512][512] fp16
    const void* bias, size_t bias_off,
    float* __restrict__ h, u16* __restrict__ hb, const int* flagp)
{
  __shared__ u16 tile[4 * 6144];
  const int t = threadIdx.x, lane = t & 63, w = t >> 6;
  const int bm = blockIdx.y << 6, bn = blockIdx.x << 7, bz = blockIdx.z;
  const int wr = w >> 1, wc = w & 1;
  const int col = lane & 15, quad = lane >> 4;

  const int srow = w * 16 + (lane >> 2);  // 0..63
  const int skol = (((lane & 3) ^ ((lane >> 3) & 3)) << 3);
  const u16* ag  = A + ((size_t)(bm + srow) * 2 + bz) * 512 + skol;
  const u16* bg0 = Wp + (size_t)bz * 512 * 512 + (size_t)(bn + srow) * 512 + skol;
  const u16* bg1 = bg0 + (size_t)64 * 512;
  u16* la  = &tile[       w * 512];
  u16* lb0 = &tile[2048 + w * 512];
  u16* lb1 = &tile[4096 + w * 512];

  #pragma unroll
  for (int p = 0; p < 3; ++p) {
    const int k0 = p << 5, bo = p * 6144;
    async16(ag  + k0, la  + bo);
    async16(bg0 + k0, lb0 + bo);
    async16(bg1 + k0, lb1 + bo);
  }
  asm volatile("s_waitcnt vmcnt(6)" ::: "memory");
  __builtin_amdgcn_s_barrier();
  asm volatile("" ::: "memory");

  const int rswz = ((col >> 1) & 3);

  f32x4 acc[2][4] = {};
  for (int t2 = 0; t2 < 16; ++t2) {
    if (t2 + 3 < 16) {
      const int k0 = (t2 + 3) << 5;
      const int bo = ((t2 + 3) & 3) * 6144;
      async16(ag  + k0, la  + bo);
      async16(bg0 + k0, lb0 + bo);
      async16(bg1 + k0, lb1 + bo);
    }
    const int cur = (t2 & 3) * 6144;
    f16x8 af[2], bf[4];
    #pragma unroll
    for (int i = 0; i < 2; i++)
      af[i] = *(const f16x8*)&tile[cur + (wr * 32 + i * 16 + col) * 32 + ((quad ^ rswz) * 8)];
    #pragma unroll
    for (int j = 0; j < 4; j++)
      bf[j] = *(const f16x8*)&tile[cur + 2048 + (wc * 64 + j * 16 + col) * 32 + ((quad ^ rswz) * 8)];
    #pragma unroll
    for (int i = 0; i < 2; i++)
      #pragma unroll
      for (int j = 0; j < 4; j++)
        acc[i][j] = __builtin_amdgcn_mfma_f32_16x16x32_f16(af[i], bf[j], acc[i][j], 0, 0, 0);
    if      (t2 + 3 < 16) asm volatile("s_waitcnt vmcnt(6)" ::: "memory");
    else if (t2 + 2 < 16) asm volatile("s_waitcnt vmcnt(3)" ::: "memory");
    else                  asm volatile("s_waitcnt vmcnt(0)" ::: "memory");
    __builtin_amdgcn_s_barrier();
    asm volatile("" ::: "memory");
  }

  const int isbf = *flagp;
  #pragma unroll
  for (int i = 0; i < 2; i++) {
    #pragma unroll
    for (int r = 0; r < 4; r++) {
      const size_t g = (size_t)(bm + wr * 32 + i * 16 + quad * 4 + r) * 2 + bz;
      #pragma unroll
      for (int j = 0; j < 4; j++) {
        const int n = bn + wc * 64 + j * 16 + col;
        float c = acc[i][j][r] + ldf(bias, bias_off + n, isbf);
        c += h[g * 512 + n];
        h[g * 512 + n] = c;
        hb[g * 512 + n] = f2h(c);
      }
    }
  }
}

// ---------------------------------------------------------------------------
// attn_acc_mfma: partial[p][b,n,vi,qi] = sum_{s in 128-chunk p} v[s,vi]*k[s,qi]
// grid (B*H, S/128). LDS-transposed staging (stride 136 = 8*17: 16B-aligned
// fragments, 2-way max read conflicts). MFMA: D[vi][qi] = sum_s Vt[vi][s]*Kt[qi][s].
// ---------------------------------------------------------------------------
#define KT_ 136
__global__ __launch_bounds__(256) void attn_acc_mfma(
    const u16* __restrict__ kbuf, const u16* __restrict__ vbuf,
    float* __restrict__ Apart)
{
  __shared__ u16 ktr[64 * KT_];
  __shared__ u16 vtr[64 * KT_];
  const int bh = blockIdx.x;              // b*H + n
  const int b  = bh >> 3, n = bh & 7;
  const int s0 = blockIdx.y << 7;         // 128 s-rows per block
  const int t = threadIdx.x, lane = t & 63, w = t >> 6;
  const int col = lane & 15, quad = lane >> 4;

  // staging: 128 rows x 16 ushort4 per tensor = 2048 u4; 8 per thread
  #pragma unroll
  for (int u = 0; u < 8; u++) {
    const int flat = u * 256 + t;
    const int row = flat >> 4, q4 = (flat & 15) << 2;
    const size_t g = ((size_t)(s0 + row) * B_ + b) * D_ + n * 64 + q4;
    ushort4 kk = *(const ushort4*)&kbuf[g];
    ushort4 vv = *(const ushort4*)&vbuf[g];
    ktr[(q4+0)*KT_ + row] = kk.x; ktr[(q4+1)*KT_ + row] = kk.y;
    ktr[(q4+2)*KT_ + row] = kk.z; ktr[(q4+3)*KT_ + row] = kk.w;
    vtr[(q4+0)*KT_ + row] = vv.x; vtr[(q4+1)*KT_ + row] = vv.y;
    vtr[(q4+2)*KT_ + row] = vv.z; vtr[(q4+3)*KT_ + row] = vv.w;
  }
  __syncthreads();

  // wave w owns vi-tile w (16 rows of A); j = qi-tile
  f32x4 acc[4] = {};
  #pragma unroll
  for (int ks = 0; ks < 4; ks++) {        // K = 128 = 4 * 32
    const int k0 = ks * 32;
    f16x8 af = *(const f16x8*)&vtr[(w * 16 + col) * KT_ + k0 + quad * 8];
    #pragma unroll
    for (int j = 0; j < 4; j++) {
      f16x8 bf = *(const f16x8*)&ktr[(j * 16 + col) * KT_ + k0 + quad * 8];
      acc[j] = __builtin_amdgcn_mfma_f32_16x16x32_f16(af, bf, acc[j], 0, 0, 0);
    }
  }
  float* Ap = Apart + ((size_t)blockIdx.y * 16 + bh) * 4096;
  #pragma unroll
  for (int j = 0; j < 4; j++)
    #pragma unroll
    for (int r = 0; r < 4; r++) {
      const int vi = w * 16 + quad * 4 + r, qi = j * 16 + col;
      Ap[vi * 64 + qi] = acc[j][r];
    }
}

// ---------------------------------------------------------------------------
// form_wp: grid (B*H = 16).  Phase 1: reduce 32 partials -> A[b,h][vi,qi],
// store fp16 TRANSPOSED in LDS aT[qi][vi].  Phase 2 (MFMA):
//   W'[b][out][h*64+qi] = sum_vi Wo[out][h*64+vi] * A[vi,qi]
// wave w computes out rows [w*128, w*128+128).
// ---------------------------------------------------------------------------
#define WPT_ 72
__global__ __launch_bounds__(256) void form_wp(
    const float* __restrict__ Apart, const u16* __restrict__ Wo16,
    u16* __restrict__ wp)
{
  __shared__ u16 aT[64 * WPT_];
  const int bh = blockIdx.x;            // b*8 + h
  const int b = bh >> 3, hh = bh & 7;
  const int t = threadIdx.x, lane = t & 63, w = t >> 6;
  const int col = lane & 15, quad = lane >> 4;

  #pragma unroll
  for (int e = 0; e < 4; e++) {
    const int idx = t * 16 + e * 4;     // 0..4095, 4-aligned
    float4 s = make_float4(0.f, 0.f, 0.f, 0.f);
    for (int p = 0; p < 32; p++) {
      const float4 v = *(const float4*)&Apart[((size_t)p * 16 + bh) * 4096 + idx];
      s.x += v.x; s.y += v.y; s.z += v.z; s.w += v.w;
    }
    const int vi = idx >> 6, qi = idx & 63;   // qi..qi+3 stay within the row
    aT[(qi + 0) * WPT_ + vi] = f2h(s.x);
    aT[(qi + 1) * WPT_ + vi] = f2h(s.y);
    aT[(qi + 2) * WPT_ + vi] = f2h(s.z);
    aT[(qi + 3) * WPT_ + vi] = f2h(s.w);
  }
  __syncthreads();

  f32x4 acc[8][4] = {};
  #pragma unroll
  for (int ks = 0; ks < 2; ks++) {
    f16x8 bf[4];
    #pragma unroll
    for (int j = 0; j < 4; j++)
      bf[j] = *(const f16x8*)&aT[(j * 16 + col) * WPT_ + ks * 32 + quad * 8];
    #pragma unroll
    for (int i = 0; i < 8; i++) {
      const int out = w * 128 + i * 16 + col;
      f16x8 af = *(const f16x8*)&Wo16[(size_t)out * 512 + hh * 64 + ks * 32 + quad * 8];
      #pragma unroll
      for (int j = 0; j < 4; j++)
        acc[i][j] = __builtin_amdgcn_mfma_f32_16x16x32_f16(af, bf[j], acc[i][j], 0, 0, 0);
    }
  }
  u16* wpb = wp + (size_t)b * 512 * 512;
  #pragma unroll
  for (int i = 0; i < 8; i++)
    #pragma unroll
    for (int r = 0; r < 4; r++) {
      const int out = w * 128 + i * 16 + quad * 4 + r;
      #pragma unroll
      for (int j = 0; j < 4; j++)
        wpb[(size_t)out * 512 + hh * 64 + j * 16 + col] = f2h(acc[i][j][r]);
    }
}

// ---------------------------------------------------------------------------
// LayerNorm over D=512 per token; reads h fp32, writes h fp32 + hb fp16.
// ---------------------------------------------------------------------------
__global__ __launch_bounds__(256) void ln_k(
    float* __restrict__ h, u16* __restrict__ hb,
    const void* g, size_t g_off, const void* be, size_t be_off, const int* flagp)
{
  const int isbf = *flagp;
  const int m = blockIdx.x, t = threadIdx.x;
  float* p = h + (size_t)m * D_;
  const float x0 = p[t], x1 = p[t + 256];
  __shared__ float red[4];
  float s = x0 + x1;
  #pragma unroll
  for (int off = 32; off >= 1; off >>= 1) s += __shfl_xor(s, off);
  if ((t & 63) == 0) red[t >> 6] = s;
  __syncthreads();
  const float mean = (red[0] + red[1] + red[2] + red[3]) * (1.f / 512.f);
  const float d0 = x0 - mean, d1 = x1 - mean;
  float s2 = d0 * d0 + d1 * d1;
  #pragma unroll
  for (int off = 32; off >= 1; off >>= 1) s2 += __shfl_xor(s2, off);
  __syncthreads();
  if ((t & 63) == 0) red[t >> 6] = s2;
  __syncthreads();
  const float var = (red[0] + red[1] + red[2] + red[3]) * (1.f / 512.f);
  const float sc = rsqrtf(var + 1e-5f);
  const float y0 = d0 * sc * ldf(g, g_off + t, isbf)       + ldf(be, be_off + t, isbf);
  const float y1 = d1 * sc * ldf(g, g_off + t + 256, isbf) + ldf(be, be_off + t + 256, isbf);
  p[t] = y0;       p[t + 256] = y1;
  hb[(size_t)m * D_ + t] = f2h(y0);
  hb[(size_t)m * D_ + t + 256] = f2h(y1);
}

// ---------------------------------------------------------------------------
extern "C" void kernel_launch(void* const* d_in, const int* in_sizes, int n_in,
                              void* d_out, int out_size, void* d_ws, size_t ws_size,
                              hipStream_t stream) {
  const int*  inp = (const int*) d_in[0];
  const void* emb = d_in[1];
  const void* Wq  = d_in[2];
  const void* bq  = d_in[3];
  const void* Wk  = d_in[4];
  const void* bk  = d_in[5];
  const void* Wv  = d_in[6];
  const void* bv  = d_in[7];
  const void* Wo  = d_in[8];
  const void* bo  = d_in[9];
  const void* W1  = d_in[10];
  const void* b1  = d_in[11];
  const void* W2  = d_in[12];
  const void* b2  = d_in[13];
  const void* g2  = d_in[14];
  const void* be2 = d_in[15];
  const void* Wfc = d_in[16];
  const void* bfc = d_in[17];

  // workspace layout (bytes)
  char* ws = (char*)d_ws;
  float* h     = (float*)(ws);                    // 16,777,216
  u16*   hb    = (u16*)  (ws + 16777216);         //  8,388,608 (fp16)
  u16*   qb    = (u16*)  (ws + 25165824);         //  8,388,608
  u16*   kb    = (u16*)  (ws + 33554432);         //  8,388,608
  u16*   vb    = (u16*)  (ws + 41943040);         //  8,388,608
  u16*   wp    = vb;                              //  1,048,576 (v dead after attn_acc;
                                                  //   W1's mid overwrite comes later)
  u16*   mid   = qb;                              // 33,554,432 (aliases q,k,v,+)
  float* Apart = (float*)(ws + 58720256);         //  8,388,608 (32 partials)
  u16*   WcAll = (u16*)  (ws + 67239936);         // 37,748,736 (6 layers fp16)
  u16*   WcFC  = (u16*)  (ws + 104988672);        //  4,194,304
  int*   flag  = (int*)  (ws + 109182976);

  detect_dtype<<<1, 64, 0, stream>>>(emb, flag);
  // one launch: all weights -> fp16  AND  token embedding (independent work)
  prep_all<<<CVT_BLKS_ + SB_, 256, 0, stream>>>(
      Wq, Wk, Wv, Wo, W1, W2, Wfc, WcAll, WcFC, inp, emb, h, hb, flag);

  const dim3 gQ64(D_ / 128, SB_ / 64);      // (4, 128) = 512 blocks (W2)
  const dim3 gWO(D_ / 128, S_ / 64, 2);     // (4, 64, 2) = 512 blocks (Wo')
  const dim3 gQKV(3 * D_ / 128, SB_ / 128); // (12, 64) fused q|k|v, 3/CU
  const dim3 gAT(B_ * H_, S_ / 128);        // (16, 32)

  for (int l = 0; l < L_; l++) {
    u16* Wcl = WcAll + (size_t)l * NTOT_;

    // fused: q = unit(h@Wq^T+bq), k = elu(unit(h@Wk^T+bk)), v = h@Wv^T+bv
    gemm_qkv<<<gQKV, 256, 0, stream>>>(hb, Wcl, bq, bk, bv, (size_t)l*D_, qb, kb, vb, D_, flag);

    attn_acc_mfma<<<gAT, 256, 0, stream>>>(kb, vb, Apart);
    // W'[b] = Wo folded with attention matrix (reduce + tiny MFMA GEMM)
    form_wp<<<B_ * H_, 256, 0, stream>>>(Apart, Wcl + 3*DD_, wp);
    // h += q @ W'[b]^T + bo   (replaces attn_apply + Wo GEMM)
    gemm_wo<<<gWO, 256, 0, stream>>>(qb, wp, bo, (size_t)l*D_, h, hb, flag);

    // mid = relu(h @ W1^T + b1)  [PERSISTENT: 1024 tiles -> 512 blocks x 2]
    gemm_pers<1,0,2,2,4,4><<<512, 256, 0, stream>>>(hb, Wcl + 4*DD_, 1, b1, (size_t)l*FF_, mid, nullptr, SB_, FF_, D_, flag);
    // h = h + mid @ W2^T + b2 (fp32 only: hb write is dead, LN rewrites it)
    gemm_mfma64<0,2,3><<<gQ64, 256, 0, stream>>>(mid, Wcl + 4*DD_ + FD_, b2, (size_t)l*D_, h, h, nullptr, SB_, D_, FF_, flag);
    ln_k<<<SB_, 256, 0, stream>>>(h, hb, g2, (size_t)l*D_, be2, (size_t)l*D_, flag);
  }

  // FC transposed: out[b][v][s] = Wfc[v,:] . hb[s*2+b,:] + bfc[v]
  // PERSISTENT: 2048 tiles -> TPB=2 -> 1024 blocks = 4/CU queued, 3/CU
  // resident (48KB LDS) -- TLP where counters showed 2/CU was the limit.
  gemm_pers<0,3,2,2,5,6><<<1024, 256, 0, stream>>>(WcFC, hb, 2, bfc, 0, nullptr, d_out, V_, S_, D_, flag);
}

// Round 10
// 1258.450 us; speedup vs baseline: 1.0708x; 1.0708x over previous
//
#include <hip/hip_runtime.h>
#include <hip/hip_bf16.h>

#define D_  512
#define H_  8
#define DH_ 64
#define L_  6
#define FF_ 2048
#define V_  4096
#define B_  2
#define S_  4096
#define SB_ (S_*B_)   // 8192 tokens
#define DD_ ((size_t)D_*D_)
#define FD_ ((size_t)FF_*D_)
#define NTOT_ (4*DD_ + 2*FD_)   // per-layer converted weight elems (3,145,728)
#define CVT_BLKS_ 20480         // blocks doing weight conversion in prep_all

typedef unsigned short u16;
typedef unsigned int   u32;
typedef _Float16 f16;
typedef f16   f16x8 __attribute__((ext_vector_type(8)));
typedef float f32x4 __attribute__((ext_vector_type(4)));

__device__ __forceinline__ float us2f(u16 u){          // bf16 bits -> float
  union { u32 i; float f; } c; c.i = ((u32)u) << 16; return c.f;
}
__device__ __forceinline__ u16 f2b(float f){           // float -> bf16 bits (RNE)
  union { float f; u32 i; } c; c.f = f;
  u32 x = c.i;
  x += 0x7FFF + ((x >> 16) & 1);
  return (u16)(x >> 16);
}
__device__ __forceinline__ float h2f(u16 u){           // fp16 bits -> float
  union { u16 s; f16 h; } c; c.s = u; return (float)c.h;
}
__device__ __forceinline__ u16 f2h(float f){           // float -> fp16 bits (RNE)
  union { f16 h; u16 s; } c; c.h = (f16)f; return c.s;
}
// load element i of external tensor p: bf16 if isbf else fp32
__device__ __forceinline__ float ldf(const void* p, size_t i, int isbf){
  return isbf ? us2f(((const u16*)p)[i]) : ((const float*)p)[i];
}

typedef const __attribute__((address_space(1))) u32* gas_u32p;
typedef       __attribute__((address_space(3))) u32* las_u32p;
// async 16B/lane global->LDS; LDS dest = wave-uniform base + lane*16
__device__ __forceinline__ void async16(const u16* g, u16* l){
  __builtin_amdgcn_global_load_lds((gas_u32p)(const void*)g, (las_u32p)(void*)l, 16, 0, 0);
}

// ---------------------------------------------------------------------------
// dtype sniffer (empirically: inputs are fp32 -> flag 0; kept for robustness)
// ---------------------------------------------------------------------------
__global__ __launch_bounds__(64) void detect_dtype(const void* emb, int* flag)
{
  const int t = threadIdx.x;
  u16 hw = ((const u16*)emb)[t];
  int e = (hw >> 7) & 0xFF;
  int ok = ((e > 96) && (e < 160)) || ((hw & 0x7FFF) == 0);
  unsigned long long m = __ballot(ok);
  if (t == 0) *flag = (__popcll(m) >= 56) ? 1 : 0;
}

// ---------------------------------------------------------------------------
// prep_all: ONE launch doing both independent prep steps (range-split):
//  blocks [0, CVT_BLKS_):       convert all weights (6 layers + Wfc) to fp16
//  blocks [CVT_BLKS_, +SB_):    embed  h/hb[(s*B+b)*D+d] = emb[tok*D+d]
// ---------------------------------------------------------------------------
__global__ __launch_bounds__(256) void prep_all(
    const void* Wq, const void* Wk, const void* Wv, const void* Wo,
    const void* W1, const void* W2, const void* Wfc,
    u16* __restrict__ dstAll, u16* __restrict__ dstFC,
    const int* __restrict__ inp, const void* emb,
    float* __restrict__ h, u16* __restrict__ hb, const int* flagp)
{
  const int isbf = *flagp;
  if (blockIdx.x >= CVT_BLKS_) {
    const int m = blockIdx.x - CVT_BLKS_;        // token index s*B + b
    const int t = threadIdx.x;
    const int s = m >> 1, b = m & 1;
    const int tok = inp[b * S_ + s];
    #pragma unroll
    for (int hh = 0; hh < 2; hh++) {
      const int d = t + hh * 256;
      const float v = ldf(emb, (size_t)tok * D_ + d, isbf);
      h[(size_t)m * D_ + d] = v;
      hb[(size_t)m * D_ + d] = f2h(v);
    }
    return;
  }
  const size_t total6 = 6 * NTOT_;
  const size_t i = ((size_t)blockIdx.x * 256 + threadIdx.x) * 4;
  const void* src; size_t off; u16* dst;
  if (i < total6) {
    const int l = (int)(i / NTOT_);
    const size_t r = i - (size_t)l * NTOT_;
    const size_t n4 = 4 * DD_, nW1 = n4 + FD_;
    if (r < n4) {
      const int wsel = (int)(r / DD_);
      src = (wsel == 0) ? Wq : (wsel == 1) ? Wk : (wsel == 2) ? Wv : Wo;
      off = (size_t)l * DD_ + (r - (size_t)wsel * DD_);
    } else if (r < nW1) { src = W1; off = (size_t)l * FD_ + (r - n4); }
    else                { src = W2; off = (size_t)l * FD_ + (r - nW1); }
    dst = dstAll + i;
  } else {
    const size_t j = i - total6;
    if (j >= (size_t)V_ * D_) return;
    src = Wfc; off = j; dst = dstFC + j;
  }
  ushort4 o;
  if (isbf) {
    ushort4 u = *(const ushort4*)((const u16*)src + off);
    o = make_ushort4(f2h(us2f(u.x)), f2h(us2f(u.y)), f2h(us2f(u.z)), f2h(us2f(u.w)));
  } else {
    float4 f = *(const float4*)((const float*)src + off);
    o = make_ushort4(f2h(f.x), f2h(f.y), f2h(f.z), f2h(f.w));
  }
  *(ushort4*)dst = o;
}

// ---------------------------------------------------------------------------
// PERSISTENT MFMA GEMM, BM=128 x BN=128, K=512 fixed (NT=16 k-steps/tile).
// Each block processes TPB output tiles with ONE continuous counted-vmcnt
// pipeline.  Tile order: v = blockIdx.x*TPB + g;
//   by = v >> LOG_TXZ (A-panel row tile; CONSTANT within a block),
//   bz = (v & (TXZ-1)) >> LOG_TX,  bx = v & (TX-1).
// Bias preloaded into registers BEFORE any staging.
//  OUTMODE 0: fp16 Cb[m*N+n], bias per-n (+relu if ACT)
//  OUTMODE 3: flag-dtype Cout[bz*M*N + m*N + n], bias per-m
// ---------------------------------------------------------------------------
template<int ACT, int OUTMODE, int PRE, int TPB, int LOG_TX, int LOG_TXZ>
__global__ __launch_bounds__(256) void gemm_pers(
    const u16* __restrict__ A, const u16* __restrict__ Bm,
    int bstride,
    const void* bias, size_t bias_off,
    u16* __restrict__ Cb, void* __restrict__ Cout,
    int M, int N, int K, const int* flagp)
{
  __shared__ u16 tile[(PRE + 1) * 8192];  // per buf: A [0,4096), B [4096,8192)
  const int t = threadIdx.x, lane = t & 63, w = t >> 6;
  const int wr = w >> 1, wc = w & 1;
  const int col = lane & 15, quad = lane >> 4;
  const int srow = w * 16 + (lane >> 2);
  const int skol = (((lane & 3) ^ ((lane >> 3) & 3)) << 3);
  const int rswz = ((col >> 1) & 3);
  const int isbf = *flagp;
  const int vbase = blockIdx.x * TPB;

  // ---- bias preload (before any staging: compiler wait is trivial here) ----
  float bpre3[(OUTMODE == 3) ? 16 : 1];
  float bpre0[(OUTMODE == 3) ? 1 : TPB][4];
  if (OUTMODE == 3) {
    const int by0 = vbase >> LOG_TXZ;            // same by for all TPB tiles
    #pragma unroll
    for (int i = 0; i < 4; i++)
      #pragma unroll
      for (int r = 0; r < 4; r++)
        bpre3[i * 4 + r] = ldf(bias, bias_off + (by0 << 7) + wr * 64 + i * 16 + quad * 4 + r, isbf);
  } else {
    #pragma unroll
    for (int g = 0; g < TPB; g++) {
      const int bxg = (vbase + g) & ((1 << LOG_TX) - 1);
      #pragma unroll
      for (int j = 0; j < 4; j++)
        bpre0[g][j] = ldf(bias, bias_off + (bxg << 7) + wc * 64 + j * 16 + col, isbf);
    }
  }

  // ---- stage-side tile pointers ----
  int st = -1;
  const u16 *ag0 = nullptr, *ag1 = nullptr, *bg0 = nullptr, *bg1 = nullptr;
  auto set_tile = [&](int tp) {
    const int v  = vbase + tp;
    const int by = v >> LOG_TXZ;
    const int rr = v & ((1 << LOG_TXZ) - 1);
    const int bz = rr >> LOG_TX;
    const int bx = rr & ((1 << LOG_TX) - 1);
    ag0 = A + (size_t)((by << 7) + srow) * K + skol;
    ag1 = ag0 + (size_t)64 * K;
    bg0 = Bm + ((size_t)((bx << 7) + srow) * bstride + bz) * K + skol;
    bg1 = bg0 + (size_t)64 * bstride * K;
  };
  auto stage = [&](int u) {
    const int tp = u >> 4;
    if (tp != st) { st = tp; set_tile(tp); }
    const int k0 = (u & 15) << 5;
    const int bo = (u % (PRE + 1)) * 8192;
    async16(ag0 + k0, &tile[bo +        w * 512]);
    async16(ag1 + k0, &tile[bo + 2048 + w * 512]);
    async16(bg0 + k0, &tile[bo + 4096 + w * 512]);
    async16(bg1 + k0, &tile[bo + 6144 + w * 512]);
  };

  const int U = TPB * 16;
  #pragma unroll
  for (int p = 0; p < PRE; ++p) stage(p);
  if (PRE >= 2) asm volatile("s_waitcnt vmcnt(4)" ::: "memory");
  else          asm volatile("s_waitcnt vmcnt(0)" ::: "memory");
  __builtin_amdgcn_s_barrier();
  asm volatile("" ::: "memory");

  f32x4 acc[4][4] = {};
  for (int u = 0; u < U; ++u) {
    if (u + PRE < U) stage(u + PRE);
    const int cur = (u % (PRE + 1)) * 8192;
    f16x8 af[4], bf[4];
    #pragma unroll
    for (int i = 0; i < 4; i++)
      af[i] = *(const f16x8*)&tile[cur + (wr * 64 + i * 16 + col) * 32 + ((quad ^ rswz) * 8)];
    #pragma unroll
    for (int j = 0; j < 4; j++)
      bf[j] = *(const f16x8*)&tile[cur + 4096 + (wc * 64 + j * 16 + col) * 32 + ((quad ^ rswz) * 8)];
    #pragma unroll
    for (int i = 0; i < 4; i++)
      #pragma unroll
      for (int j = 0; j < 4; j++)
        acc[i][j] = __builtin_amdgcn_mfma_f32_16x16x32_f16(af[i], bf[j], acc[i][j], 0, 0, 0);

    if ((u & 15) == 15) {
      // -------- epilogue for tile (u>>4); registers + stores only --------
      const int v  = vbase + (u >> 4);
      const int by = v >> LOG_TXZ;
      const int rr = v & ((1 << LOG_TXZ) - 1);
      const int bz = rr >> LOG_TX;
      const int bx = rr & ((1 << LOG_TX) - 1);
      const int bm = by << 7, bn = bx << 7;
      if (OUTMODE == 3) {
        const size_t obase = (size_t)bz * M * N;
        #pragma unroll
        for (int i = 0; i < 4; i++)
          #pragma unroll
          for (int r = 0; r < 4; r++) {
            const int m = bm + wr * 64 + i * 16 + quad * 4 + r;
            #pragma unroll
            for (int j = 0; j < 4; j++) {
              const int n = bn + wc * 64 + j * 16 + col;
              const float c = acc[i][j][r] + bpre3[i * 4 + r];
              const size_t oi = obase + (size_t)m * N + n;
              if (isbf) ((u16*)Cout)[oi] = f2b(c);
              else      ((float*)Cout)[oi] = c;
            }
          }
      } else {
        const int g = u >> 4;
        #pragma unroll
        for (int i = 0; i < 4; i++)
          #pragma unroll
          for (int r = 0; r < 4; r++) {
            const int m = bm + wr * 64 + i * 16 + quad * 4 + r;
            #pragma unroll
            for (int j = 0; j < 4; j++) {
              const int n = bn + wc * 64 + j * 16 + col;
              float c = acc[i][j][r] + bpre0[g][j];
              if (ACT == 1) c = fmaxf(c, 0.f);
              Cb[(size_t)m * N + n] = f2h(c);
            }
          }
      }
      const f32x4 z = {0.f, 0.f, 0.f, 0.f};
      #pragma unroll
      for (int i = 0; i < 4; i++)
        #pragma unroll
        for (int j = 0; j < 4; j++)
          acc[i][j] = z;
    }

    if (PRE >= 2 && u + 2 < U) asm volatile("s_waitcnt vmcnt(4)" ::: "memory");
    else                       asm volatile("s_waitcnt vmcnt(0)" ::: "memory");
    __builtin_amdgcn_s_barrier();
    asm volatile("" ::: "memory");
  }
}

// ---------------------------------------------------------------------------
// Fused QKV GEMM: N = 1536 (Wc holds q|k|v rows contiguous). grid (12, 64)
// -> 768 blocks = 3 blocks/CU. Epilogue per 64-col wave span (head-aligned):
//   cols 0-511 (Q): unit -> qb | 512-1023 (K): elu(unit) -> kb | 1024+ (V) -> vb
// PRE=2 counted-vmcnt pipeline.
// ---------------------------------------------------------------------------
__global__ __launch_bounds__(256) void gemm_qkv(
    const u16* __restrict__ A, const u16* __restrict__ Bm,
    const void* bq, const void* bk, const void* bv, size_t b_off,
    u16* __restrict__ qb, u16* __restrict__ kb, u16* __restrict__ vb,
    int K, const int* flagp)
{
  __shared__ u16 tile[3 * 8192];
  const int t = threadIdx.x, lane = t & 63, w = t >> 6;
  const int bm = blockIdx.y << 7, bn = blockIdx.x << 7;
  const int wr = w >> 1, wc = w & 1;
  const int col = lane & 15, quad = lane >> 4;

  const int srow = w * 16 + (lane >> 2);
  const int skol = (((lane & 3) ^ ((lane >> 3) & 3)) << 3);
  const u16* ag0 = A + (size_t)(bm + srow) * K + skol;
  const u16* ag1 = A + (size_t)(bm + 64 + srow) * K + skol;
  const u16* bg0 = Bm + (size_t)(bn + srow) * K + skol;
  const u16* bg1 = Bm + (size_t)(bn + 64 + srow) * K + skol;
  u16* la0 = &tile[       w * 512];
  u16* la1 = &tile[2048 + w * 512];
  u16* lb0 = &tile[4096 + w * 512];
  u16* lb1 = &tile[6144 + w * 512];

  const int nt = K >> 5;

  #pragma unroll
  for (int p = 0; p < 2; ++p) {
    const int k0 = p << 5, bo = p * 8192;
    async16(ag0 + k0, la0 + bo);
    async16(ag1 + k0, la1 + bo);
    async16(bg0 + k0, lb0 + bo);
    async16(bg1 + k0, lb1 + bo);
  }
  asm volatile("s_waitcnt vmcnt(4)" ::: "memory");
  __builtin_amdgcn_s_barrier();
  asm volatile("" ::: "memory");

  const int rswz = ((col >> 1) & 3);

  f32x4 acc[4][4] = {};
  for (int t2 = 0; t2 < nt; ++t2) {
    if (t2 + 2 < nt) {
      const int k0 = (t2 + 2) << 5;
      const int bo = ((t2 + 2) % 3) * 8192;
      async16(ag0 + k0, la0 + bo);
      async16(ag1 + k0, la1 + bo);
      async16(bg0 + k0, lb0 + bo);
      async16(bg1 + k0, lb1 + bo);
    }
    const int cur = (t2 % 3) * 8192;
    f16x8 af[4], bf[4];
    #pragma unroll
    for (int i = 0; i < 4; i++)
      af[i] = *(const f16x8*)&tile[cur + (wr * 64 + i * 16 + col) * 32 + ((quad ^ rswz) * 8)];
    #pragma unroll
    for (int j = 0; j < 4; j++)
      bf[j] = *(const f16x8*)&tile[cur + 4096 + (wc * 64 + j * 16 + col) * 32 + ((quad ^ rswz) * 8)];
    #pragma unroll
    for (int i = 0; i < 4; i++)
      #pragma unroll
      for (int j = 0; j < 4; j++)
        acc[i][j] = __builtin_amdgcn_mfma_f32_16x16x32_f16(af[i], bf[j], acc[i][j], 0, 0, 0);
    if (t2 + 2 < nt) asm volatile("s_waitcnt vmcnt(4)" ::: "memory");
    else             asm volatile("s_waitcnt vmcnt(0)" ::: "memory");
    __builtin_amdgcn_s_barrier();
    asm volatile("" ::: "memory");
  }

  const int isbf = *flagp;
  const int nbase = bn + wc * 64;       // 64-aligned -> head-aligned
  const int sel = nbase >> 9;           // 0=Q 1=K 2=V, wave-uniform
  const int nl0 = nbase & 511;          // local col base within the matrix
  u16* outp = (sel == 0) ? qb : (sel == 1) ? kb : vb;
  const void* bias = (sel == 0) ? bq : (sel == 1) ? bk : bv;

  if (sel < 2) {
    #pragma unroll
    for (int i = 0; i < 4; i++) {
      #pragma unroll
      for (int r = 0; r < 4; r++) {
        float v[4]; float ss = 0.f;
        #pragma unroll
        for (int j = 0; j < 4; j++) {
          const int nl = nl0 + j * 16 + col;
          v[j] = acc[i][j][r] + ldf(bias, b_off + nl, isbf);
          ss += v[j] * v[j];
        }
        ss += __shfl_xor(ss, 1); ss += __shfl_xor(ss, 2);
        ss += __shfl_xor(ss, 4); ss += __shfl_xor(ss, 8);
        const float inv = rsqrtf(fmaxf(ss, 1e-30f));
        const int m = bm + wr * 64 + i * 16 + quad * 4 + r;
        #pragma unroll
        for (int j = 0; j < 4; j++) {
          float u = v[j] * inv;
          if (sel == 1) u = (u > 0.f) ? u : expm1f(u);
          outp[(size_t)m * 512 + nl0 + j * 16 + col] = f2h(u);
        }
      }
    }
  } else {
    #pragma unroll
    for (int i = 0; i < 4; i++)
      #pragma unroll
      for (int r = 0; r < 4; r++) {
        const int m = bm + wr * 64 + i * 16 + quad * 4 + r;
        #pragma unroll
        for (int j = 0; j < 4; j++) {
          const int nl = nl0 + j * 16 + col;
          outp[(size_t)m * 512 + nl] = f2h(acc[i][j][r] + ldf(bias, b_off + nl, isbf));
        }
      }
  }
}

// ---------------------------------------------------------------------------
// MFMA GEMM, BM=64 x BN=128: thin-N (W2: N=512). 512 blocks = 2 blocks/CU.
// OUTMODE 2 = fp32 only (W2: fp16 hb write is dead, LN rewrites it).
// ---------------------------------------------------------------------------
template<int ACT, int OUTMODE, int PRE>
__global__ __launch_bounds__(256) void gemm_mfma64(
    const u16* __restrict__ A, const u16* __restrict__ Bm,
    const void* bias, size_t bias_off,
    const float* __restrict__ res,
    float* __restrict__ Cf, u16* __restrict__ Cb,
    int M, int N, int K, const int* flagp)
{
  __shared__ u16 tile[(PRE + 1) * 6144];  // per buf: A [0,2048), B [2048,6144)
  const int t = threadIdx.x, lane = t & 63, w = t >> 6;
  const int bm = blockIdx.y << 6, bn = blockIdx.x << 7;
  const int wr = w >> 1, wc = w & 1;
  const int col = lane & 15, quad = lane >> 4;

  const int srow = w * 16 + (lane >> 2);  // 0..63
  const int skol = (((lane & 3) ^ ((lane >> 3) & 3)) << 3);
  const u16* ag  = A + (size_t)(bm + srow) * K + skol;
  const u16* bg0 = Bm + (size_t)(bn + srow) * K + skol;
  const u16* bg1 = Bm + (size_t)(bn + 64 + srow) * K + skol;
  u16* la  = &tile[       w * 512];
  u16* lb0 = &tile[2048 + w * 512];
  u16* lb1 = &tile[4096 + w * 512];

  const int nt = K >> 5;

  #pragma unroll
  for (int p = 0; p < PRE; ++p) {
    const int k0 = p << 5, bo = p * 6144;
    async16(ag  + k0, la  + bo);
    async16(bg0 + k0, lb0 + bo);
    async16(bg1 + k0, lb1 + bo);
  }
  if      (PRE >= 3) asm volatile("s_waitcnt vmcnt(6)" ::: "memory");
  else if (PRE == 2) asm volatile("s_waitcnt vmcnt(3)" ::: "memory");
  else               asm volatile("s_waitcnt vmcnt(0)" ::: "memory");
  __builtin_amdgcn_s_barrier();
  asm volatile("" ::: "memory");

  const int rswz = ((col >> 1) & 3);

  f32x4 acc[2][4] = {};
  for (int t2 = 0; t2 < nt; ++t2) {
    if (t2 + PRE < nt) {
      const int k0 = (t2 + PRE) << 5;
      const int bo = ((t2 + PRE) % (PRE + 1)) * 6144;
      async16(ag  + k0, la  + bo);
      async16(bg0 + k0, lb0 + bo);
      async16(bg1 + k0, lb1 + bo);
    }
    const int cur = (t2 % (PRE + 1)) * 6144;
    f16x8 af[2], bf[4];
    #pragma unroll
    for (int i = 0; i < 2; i++)
      af[i] = *(const f16x8*)&tile[cur + (wr * 32 + i * 16 + col) * 32 + ((quad ^ rswz) * 8)];
    #pragma unroll
    for (int j = 0; j < 4; j++)
      bf[j] = *(const f16x8*)&tile[cur + 2048 + (wc * 64 + j * 16 + col) * 32 + ((quad ^ rswz) * 8)];
    #pragma unroll
    for (int i = 0; i < 2; i++)
      #pragma unroll
      for (int j = 0; j < 4; j++)
        acc[i][j] = __builtin_amdgcn_mfma_f32_16x16x32_f16(af[i], bf[j], acc[i][j], 0, 0, 0);
    if (PRE >= 3) {
      if      (t2 + 3 < nt) asm volatile("s_waitcnt vmcnt(6)" ::: "memory");
      else if (t2 + 2 < nt) asm volatile("s_waitcnt vmcnt(3)" ::: "memory");
      else                  asm volatile("s_waitcnt vmcnt(0)" ::: "memory");
    } else if (PRE == 2) {
      if (t2 + 2 < nt) asm volatile("s_waitcnt vmcnt(3)" ::: "memory");
      else             asm volatile("s_waitcnt vmcnt(0)" ::: "memory");
    } else {
      asm volatile("s_waitcnt vmcnt(0)" ::: "memory");
    }
    __builtin_amdgcn_s_barrier();
    asm volatile("" ::: "memory");
  }

  const int isbf = *flagp;
  #pragma unroll
  for (int i = 0; i < 2; i++) {
    #pragma unroll
    for (int r = 0; r < 4; r++) {
      const int m = bm + wr * 32 + i * 16 + quad * 4 + r;
      #pragma unroll
      for (int j = 0; j < 4; j++) {
        const int n = bn + wc * 64 + j * 16 + col;
        float c = acc[i][j][r] + ldf(bias, bias_off + n, isbf);
        if (res) c += res[(size_t)m * N + n];
        if (ACT == 1) c = fmaxf(c, 0.f);
        if (OUTMODE == 0) {
          Cb[(size_t)m * N + n] = f2h(c);
        } else if (OUTMODE == 1) {
          Cf[(size_t)m * N + n] = c;
          Cb[(size_t)m * N + n] = f2h(c);
        } else {   // OUTMODE 2: fp32 only
          Cf[(size_t)m * N + n] = c;
        }
      }
    }
  }
}

// ---------------------------------------------------------------------------
// gemm_wo: h[g] += q[g] @ W'[b]^T + bo   with g = (bm+m)*2 + bz (batch rows
// interleaved; bz = blockIdx.z = batch).  BM=64 x BN=128, K=512, PRE=3.
// Writes h fp32 + hb fp16.  Replaces attn_apply + Wo GEMM (W' = Wo folded
// with the attention matrix, computed by form_wp).
// ---------------------------------------------------------------------------
__global__ __launch_bounds__(256) void gemm_wo(
    const u16* __restrict__ A,       // qb: rows s*2+b, 512 cols
    const u16* __restrict__ Wp,      // wp: [b][512][512] fp16
    const void* bias, size_t bias_off,
    float* __restrict__ h, u16* __restrict__ hb, const int* flagp)
{
  __shared__ u16 tile[4 * 6144];
  const int t = threadIdx.x, lane = t & 63, w = t >> 6;
  const int bm = blockIdx.y << 6, bn = blockIdx.x << 7, bz = blockIdx.z;
  const int wr = w >> 1, wc = w & 1;
  const int col = lane & 15, quad = lane >> 4;

  const int srow = w * 16 + (lane >> 2);  // 0..63
  const int skol = (((lane & 3) ^ ((lane >> 3) & 3)) << 3);
  const u16* ag  = A + ((size_t)(bm + srow) * 2 + bz) * 512 + skol;
  const u16* bg0 = Wp + (size_t)bz * 512 * 512 + (size_t)(bn + srow) * 512 + skol;
  const u16* bg1 = bg0 + (size_t)64 * 512;
  u16* la  = &tile[       w * 512];
  u16* lb0 = &tile[2048 + w * 512];
  u16* lb1 = &tile[4096 + w * 512];

  #pragma unroll
  for (int p = 0; p < 3; ++p) {
    const int k0 = p << 5, bo = p * 6144;
    async16(ag  + k0, la  + bo);
    async16(bg0 + k0, lb0 + bo);
    async16(bg1 + k0, lb1 + bo);
  }
  asm volatile("s_waitcnt vmcnt(6)" ::: "memory");
  __builtin_amdgcn_s_barrier();
  asm volatile("" ::: "memory");

  const int rswz = ((col >> 1) & 3);

  f32x4 acc[2][4] = {};
  for (int t2 = 0; t2 < 16; ++t2) {
    if (t2 + 3 < 16) {
      const int k0 = (t2 + 3) << 5;
      const int bo = ((t2 + 3) & 3) * 6144;
      async16(ag  + k0, la  + bo);
      async16(bg0 + k0, lb0 + bo);
      async16(bg1 + k0, lb1 + bo);
    }
    const int cur = (t2 & 3) * 6144;
    f16x8 af[2], bf[4];
    #pragma unroll
    for (int i = 0; i < 2; i++)
      af[i] = *(const f16x8*)&tile[cur + (wr * 32 + i * 16 + col) * 32 + ((quad ^ rswz) * 8)];
    #pragma unroll
    for (int j = 0; j < 4; j++)
      bf[j] = *(const f16x8*)&tile[cur + 2048 + (wc * 64 + j * 16 + col) * 32 + ((quad ^ rswz) * 8)];
    #pragma unroll
    for (int i = 0; i < 2; i++)
      #pragma unroll
      for (int j = 0; j < 4; j++)
        acc[i][j] = __builtin_amdgcn_mfma_f32_16x16x32_f16(af[i], bf[j], acc[i][j], 0, 0, 0);
    if      (t2 + 3 < 16) asm volatile("s_waitcnt vmcnt(6)" ::: "memory");
    else if (t2 + 2 < 16) asm volatile("s_waitcnt vmcnt(3)" ::: "memory");
    else                  asm volatile("s_waitcnt vmcnt(0)" ::: "memory");
    __builtin_amdgcn_s_barrier();
    asm volatile("" ::: "memory");
  }

  const int isbf = *flagp;
  #pragma unroll
  for (int i = 0; i < 2; i++) {
    #pragma unroll
    for (int r = 0; r < 4; r++) {
      const size_t g = (size_t)(bm + wr * 32 + i * 16 + quad * 4 + r) * 2 + bz;
      #pragma unroll
      for (int j = 0; j < 4; j++) {
        const int n = bn + wc * 64 + j * 16 + col;
        float c = acc[i][j][r] + ldf(bias, bias_off + n, isbf);
        c += h[g * 512 + n];
        h[g * 512 + n] = c;
        hb[g * 512 + n] = f2h(c);
      }
    }
  }
}

// ---------------------------------------------------------------------------
// attn_acc_mfma: partial[p][b,n,vi,qi] = sum_{s in 128-chunk p} v[s,vi]*k[s,qi]
// grid (B*H, S/128). LDS-transposed staging (stride 136 = 8*17: 16B-aligned
// fragments, 2-way max read conflicts). MFMA: D[vi][qi] = sum_s Vt[vi][s]*Kt[qi][s].
// ---------------------------------------------------------------------------
#define KT_ 136
__global__ __launch_bounds__(256) void attn_acc_mfma(
    const u16* __restrict__ kbuf, const u16* __restrict__ vbuf,
    float* __restrict__ Apart)
{
  __shared__ u16 ktr[64 * KT_];
  __shared__ u16 vtr[64 * KT_];
  const int bh = blockIdx.x;              // b*H + n
  const int b  = bh >> 3, n = bh & 7;
  const int s0 = blockIdx.y << 7;         // 128 s-rows per block
  const int t = threadIdx.x, lane = t & 63, w = t >> 6;
  const int col = lane & 15, quad = lane >> 4;

  // staging: 128 rows x 16 ushort4 per tensor = 2048 u4; 8 per thread
  #pragma unroll
  for (int u = 0; u < 8; u++) {
    const int flat = u * 256 + t;
    const int row = flat >> 4, q4 = (flat & 15) << 2;
    const size_t g = ((size_t)(s0 + row) * B_ + b) * D_ + n * 64 + q4;
    ushort4 kk = *(const ushort4*)&kbuf[g];
    ushort4 vv = *(const ushort4*)&vbuf[g];
    ktr[(q4+0)*KT_ + row] = kk.x; ktr[(q4+1)*KT_ + row] = kk.y;
    ktr[(q4+2)*KT_ + row] = kk.z; ktr[(q4+3)*KT_ + row] = kk.w;
    vtr[(q4+0)*KT_ + row] = vv.x; vtr[(q4+1)*KT_ + row] = vv.y;
    vtr[(q4+2)*KT_ + row] = vv.z; vtr[(q4+3)*KT_ + row] = vv.w;
  }
  __syncthreads();

  // wave w owns vi-tile w (16 rows of A); j = qi-tile
  f32x4 acc[4] = {};
  #pragma unroll
  for (int ks = 0; ks < 4; ks++) {        // K = 128 = 4 * 32
    const int k0 = ks * 32;
    f16x8 af = *(const f16x8*)&vtr[(w * 16 + col) * KT_ + k0 + quad * 8];
    #pragma unroll
    for (int j = 0; j < 4; j++) {
      f16x8 bf = *(const f16x8*)&ktr[(j * 16 + col) * KT_ + k0 + quad * 8];
      acc[j] = __builtin_amdgcn_mfma_f32_16x16x32_f16(af, bf, acc[j], 0, 0, 0);
    }
  }
  float* Ap = Apart + ((size_t)blockIdx.y * 16 + bh) * 4096;
  #pragma unroll
  for (int j = 0; j < 4; j++)
    #pragma unroll
    for (int r = 0; r < 4; r++) {
      const int vi = w * 16 + quad * 4 + r, qi = j * 16 + col;
      Ap[vi * 64 + qi] = acc[j][r];
    }
}

// ---------------------------------------------------------------------------
// reduce 32 partials -> fp16 A_h[bh*4096 + vi*64 + qi]  (256 blocks: BW-bound
// reduction stays wide; the parallelism-starved 16-block reduce was R9's bug)
// ---------------------------------------------------------------------------
__global__ __launch_bounds__(256) void reduce_A(
    const float* __restrict__ Apart, u16* __restrict__ Ah)
{
  const int i = blockIdx.x * 256 + threadIdx.x;   // 0..65535
  const int bh = i >> 12, idx = i & 4095;
  float s = 0.f;
  #pragma unroll
  for (int p = 0; p < 32; p++)
    s += Apart[((size_t)p * 16 + bh) * 4096 + idx];
  Ah[i] = f2h(s);
}

// ---------------------------------------------------------------------------
// form_wp: grid (B*H = 16).  Phase 1: load fp16 Ah[bh] (8 KB) into LDS
// TRANSPOSED aT[qi][vi].  Phase 2 (mini-GEMM):
//   W'[b][out][h*64+qi] = sum_vi Wo[out][h*64+vi] * A[vi,qi]
// wave w computes out rows [w*128, w*128+128).
// ---------------------------------------------------------------------------
#define WPT_ 72
__global__ __launch_bounds__(256) void form_wp(
    const u16* __restrict__ Ah, const u16* __restrict__ Wo16,
    u16* __restrict__ wp)
{
  __shared__ u16 aT[64 * WPT_];
  const int bh = blockIdx.x;            // b*8 + h
  const int b = bh >> 3, hh = bh & 7;
  const int t = threadIdx.x, lane = t & 63, w = t >> 6;
  const int col = lane & 15, quad = lane >> 4;

  #pragma unroll
  for (int e = 0; e < 4; e++) {
    const int idx = t * 16 + e * 4;     // 0..4095, 4-aligned
    const ushort4 v = *(const ushort4*)&Ah[(size_t)bh * 4096 + idx];
    const int vi = idx >> 6, qi = idx & 63;   // qi..qi+3 stay within the row
    aT[(qi + 0) * WPT_ + vi] = v.x;
    aT[(qi + 1) * WPT_ + vi] = v.y;
    aT[(qi + 2) * WPT_ + vi] = v.z;
    aT[(qi + 3) * WPT_ + vi] = v.w;
  }
  __syncthreads();

  f32x4 acc[8][4] = {};
  #pragma unroll
  for (int ks = 0; ks < 2; ks++) {
    f16x8 bf[4];
    #pragma unroll
    for (int j = 0; j < 4; j++)
      bf[j] = *(const f16x8*)&aT[(j * 16 + col) * WPT_ + ks * 32 + quad * 8];
    #pragma unroll
    for (int i = 0; i < 8; i++) {
      const int out = w * 128 + i * 16 + col;
      f16x8 af = *(const f16x8*)&Wo16[(size_t)out * 512 + hh * 64 + ks * 32 + quad * 8];
      #pragma unroll
      for (int j = 0; j < 4; j++)
        acc[i][j] = __builtin_amdgcn_mfma_f32_16x16x32_f16(af, bf[j], acc[i][j], 0, 0, 0);
    }
  }
  u16* wpb = wp + (size_t)b * 512 * 512;
  #pragma unroll
  for (int i = 0; i < 8; i++)
    #pragma unroll
    for (int r = 0; r < 4; r++) {
      const int out = w * 128 + i * 16 + quad * 4 + r;
      #pragma unroll
      for (int j = 0; j < 4; j++)
        wpb[(size_t)out * 512 + hh * 64 + j * 16 + col] = f2h(acc[i][j][r]);
    }
}

// ---------------------------------------------------------------------------
// LayerNorm over D=512 per token; reads h fp32, writes h fp32 + hb fp16.
// ---------------------------------------------------------------------------
__global__ __launch_bounds__(256) void ln_k(
    float* __restrict__ h, u16* __restrict__ hb,
    const void* g, size_t g_off, const void* be, size_t be_off, const int* flagp)
{
  const int isbf = *flagp;
  const int m = blockIdx.x, t = threadIdx.x;
  float* p = h + (size_t)m * D_;
  const float x0 = p[t], x1 = p[t + 256];
  __shared__ float red[4];
  float s = x0 + x1;
  #pragma unroll
  for (int off = 32; off >= 1; off >>= 1) s += __shfl_xor(s, off);
  if ((t & 63) == 0) red[t >> 6] = s;
  __syncthreads();
  const float mean = (red[0] + red[1] + red[2] + red[3]) * (1.f / 512.f);
  const float d0 = x0 - mean, d1 = x1 - mean;
  float s2 = d0 * d0 + d1 * d1;
  #pragma unroll
  for (int off = 32; off >= 1; off >>= 1) s2 += __shfl_xor(s2, off);
  __syncthreads();
  if ((t & 63) == 0) red[t >> 6] = s2;
  __syncthreads();
  const float var = (red[0] + red[1] + red[2] + red[3]) * (1.f / 512.f);
  const float sc = rsqrtf(var + 1e-5f);
  const float y0 = d0 * sc * ldf(g, g_off + t, isbf)       + ldf(be, be_off + t, isbf);
  const float y1 = d1 * sc * ldf(g, g_off + t + 256, isbf) + ldf(be, be_off + t + 256, isbf);
  p[t] = y0;       p[t + 256] = y1;
  hb[(size_t)m * D_ + t] = f2h(y0);
  hb[(size_t)m * D_ + t + 256] = f2h(y1);
}

// ---------------------------------------------------------------------------
extern "C" void kernel_launch(void* const* d_in, const int* in_sizes, int n_in,
                              void* d_out, int out_size, void* d_ws, size_t ws_size,
                              hipStream_t stream) {
  const int*  inp = (const int*) d_in[0];
  const void* emb = d_in[1];
  const void* Wq  = d_in[2];
  const void* bq  = d_in[3];
  const void* Wk  = d_in[4];
  const void* bk  = d_in[5];
  const void* Wv  = d_in[6];
  const void* bv  = d_in[7];
  const void* Wo  = d_in[8];
  const void* bo  = d_in[9];
  const void* W1  = d_in[10];
  const void* b1  = d_in[11];
  const void* W2  = d_in[12];
  const void* b2  = d_in[13];
  const void* g2  = d_in[14];
  const void* be2 = d_in[15];
  const void* Wfc = d_in[16];
  const void* bfc = d_in[17];

  // workspace layout (bytes)
  char* ws = (char*)d_ws;
  float* h     = (float*)(ws);                    // 16,777,216
  u16*   hb    = (u16*)  (ws + 16777216);         //  8,388,608 (fp16)
  u16*   qb    = (u16*)  (ws + 25165824);         //  8,388,608
  u16*   kb    = (u16*)  (ws + 33554432);         //  8,388,608
  u16*   vb    = (u16*)  (ws + 41943040);         //  8,388,608
  u16*   wp    = vb;                              //  1,048,576 (v dead after attn_acc;
                                                  //   W1's mid overwrite comes later)
  u16*   mid   = qb;                              // 33,554,432 (aliases q,k,v,+)
  float* Apart = (float*)(ws + 58720256);         //  8,388,608 (32 partials)
  u16*   Ah16  = (u16*)  (ws + 67108864);         //    131,072
  u16*   WcAll = (u16*)  (ws + 67239936);         // 37,748,736 (6 layers fp16)
  u16*   WcFC  = (u16*)  (ws + 104988672);        //  4,194,304
  int*   flag  = (int*)  (ws + 109182976);

  detect_dtype<<<1, 64, 0, stream>>>(emb, flag);
  // one launch: all weights -> fp16  AND  token embedding (independent work)
  prep_all<<<CVT_BLKS_ + SB_, 256, 0, stream>>>(
      Wq, Wk, Wv, Wo, W1, W2, Wfc, WcAll, WcFC, inp, emb, h, hb, flag);

  const dim3 gQ64(D_ / 128, SB_ / 64);      // (4, 128) = 512 blocks (W2)
  const dim3 gWO(D_ / 128, S_ / 64, 2);     // (4, 64, 2) = 512 blocks (Wo')
  const dim3 gQKV(3 * D_ / 128, SB_ / 128); // (12, 64) fused q|k|v, 3/CU
  const dim3 gAT(B_ * H_, S_ / 128);        // (16, 32)

  for (int l = 0; l < L_; l++) {
    u16* Wcl = WcAll + (size_t)l * NTOT_;

    // fused: q = unit(h@Wq^T+bq), k = elu(unit(h@Wk^T+bk)), v = h@Wv^T+bv
    gemm_qkv<<<gQKV, 256, 0, stream>>>(hb, Wcl, bq, bk, bv, (size_t)l*D_, qb, kb, vb, D_, flag);

    attn_acc_mfma<<<gAT, 256, 0, stream>>>(kb, vb, Apart);
    // wide 256-block reduce (BW-bound part), then tiny 16-block mini-GEMM
    reduce_A<<<256, 256, 0, stream>>>(Apart, Ah16);
    form_wp<<<B_ * H_, 256, 0, stream>>>(Ah16, Wcl + 3*DD_, wp);
    // h += q @ W'[b]^T + bo   (replaces attn_apply + Wo GEMM)
    gemm_wo<<<gWO, 256, 0, stream>>>(qb, wp, bo, (size_t)l*D_, h, hb, flag);

    // mid = relu(h @ W1^T + b1)  [PERSISTENT: 1024 tiles -> 512 blocks x 2]
    gemm_pers<1,0,2,2,4,4><<<512, 256, 0, stream>>>(hb, Wcl + 4*DD_, 1, b1, (size_t)l*FF_, mid, nullptr, SB_, FF_, D_, flag);
    // h = h + mid @ W2^T + b2 (fp32 only: hb write is dead, LN rewrites it)
    gemm_mfma64<0,2,3><<<gQ64, 256, 0, stream>>>(mid, Wcl + 4*DD_ + FD_, b2, (size_t)l*D_, h, h, nullptr, SB_, D_, FF_, flag);
    ln_k<<<SB_, 256, 0, stream>>>(h, hb, g2, (size_t)l*D_, be2, (size_t)l*D_, flag);
  }

  // FC transposed: out[b][v][s] = Wfc[v,:] . hb[s*2+b,:] + bfc[v]
  // PERSISTENT: 2048 tiles -> TPB=2 -> 1024 blocks = 4/CU queued, 3/CU
  // resident (48KB LDS) -- TLP where counters showed 2/CU was the limit.
  gemm_pers<0,3,2,2,5,6><<<1024, 256, 0, stream>>>(WcFC, hb, 2, bfc, 0, nullptr, d_out, V_, S_, D_, flag);
}